// Round 1
// baseline (264.515 us; speedup 1.0000x reference)
//
#include <hip/hip_runtime.h>
#include <stdint.h>
#include <stddef.h>

// ---------------------------------------------------------------------------
// AttentionLayer: x[4,2048,1024] f32, W_qkv[3072,1024], b_qkv[3072],
//                 W_proj[1024,1024], b_proj[1024]  -> out[4,2048,1024] f32
// Strategy: bf16 MFMA GEMMs (m97-style 128x128 tile, BK=32, global_load_lds),
// all GEMMs in NT form (both operands K-major). V transposed once so PV is NT.
// ---------------------------------------------------------------------------

typedef __attribute__((ext_vector_type(8))) short bf16x8;
typedef __attribute__((ext_vector_type(4))) float f32x4;

__device__ __forceinline__ unsigned short f2bf(float f) {
  unsigned u = __float_as_uint(f);
  u += 0x7fffu + ((u >> 16) & 1u);   // round-to-nearest-even
  return (unsigned short)(u >> 16);
}
__device__ __forceinline__ float bf2f(unsigned short h) {
  return __uint_as_float(((unsigned)h) << 16);
}

typedef const __attribute__((address_space(1))) void* gas_ptr;
typedef __attribute__((address_space(3))) void* las_ptr;

__device__ __forceinline__ void gload_lds16(const void* g, void* l) {
  // async global->LDS, 16B per lane; LDS dest = wave-uniform base + lane*16
  __builtin_amdgcn_global_load_lds((gas_ptr)(uintptr_t)g,
                                   (las_ptr)(uint32_t)(uintptr_t)l, 16, 0, 0);
}

// --------------------------- fp32 -> bf16 cast -----------------------------
__global__ __launch_bounds__(256) void cvt_f32_bf16(
    const float* __restrict__ in, unsigned short* __restrict__ out, int n) {
  int i = (blockIdx.x * blockDim.x + threadIdx.x) * 4;
  int stride = gridDim.x * blockDim.x * 4;
  for (; i < n; i += stride) {
    float4 v = *reinterpret_cast<const float4*>(in + i);
    ushort4 o;
    o.x = f2bf(v.x); o.y = f2bf(v.y); o.z = f2bf(v.z); o.w = f2bf(v.w);
    *reinterpret_cast<ushort4*>(out + i) = o;
  }
}

// --------------------------- NT bf16 GEMM ----------------------------------
// C[m,n] = alpha * sum_k A[m,k]*B[n,k]  (+ bias[n])
// A: [M,K] lda (bf16), B: [N,K] ldb (bf16). Batched via blockIdx.z strides.
// 128x128 tile, BK=32, 4 waves (2x2), each wave 64x64 via 4x4 16x16x32 MFMAs.
template <bool OUT_BF16, bool HAS_BIAS>
__global__ __launch_bounds__(256) void gemm_nt(
    const unsigned short* __restrict__ A, const unsigned short* __restrict__ B,
    void* __restrict__ Cv, const float* __restrict__ bias,
    int M, int N, int K, int lda, int ldb, int ldc,
    long long strideA, long long strideB, long long strideC, float alpha) {
  __shared__ unsigned short sA[128 * 32];
  __shared__ unsigned short sB[128 * 32];

  const int bz = blockIdx.z;
  A += (size_t)bz * (size_t)strideA;
  B += (size_t)bz * (size_t)strideB;

  const int tid = threadIdx.x;
  const int wid = tid >> 6;
  const int lane = tid & 63;
  const int wr = wid >> 1, wc = wid & 1;

  const int rowBase = blockIdx.y * 128;
  const int colBase = blockIdx.x * 128;

  f32x4 acc[4][4] = {};

  for (int k0 = 0; k0 < K; k0 += 32) {
    // stage A tile [128][32] and B tile [128][32] (K-major, linear in LDS)
#pragma unroll
    for (int i = 0; i < 2; ++i) {
      int c = i * 256 + wid * 64 + lane;
      int r = c >> 2, col = (c & 3) * 8;
      gload_lds16(A + (size_t)(rowBase + r) * lda + k0 + col,
                  &sA[(i * 256 + wid * 64) * 8]);
    }
#pragma unroll
    for (int i = 0; i < 2; ++i) {
      int c = i * 256 + wid * 64 + lane;
      int r = c >> 2, col = (c & 3) * 8;
      gload_lds16(B + (size_t)(colBase + r) * ldb + k0 + col,
                  &sB[(i * 256 + wid * 64) * 8]);
    }
    __syncthreads();  // drains vmcnt before any LDS read

    const int fr = lane & 15, kg = (lane >> 4) * 8;
    bf16x8 af[4], bfr[4];
#pragma unroll
    for (int m = 0; m < 4; ++m)
      af[m] = *reinterpret_cast<const bf16x8*>(&sA[(wr * 64 + m * 16 + fr) * 32 + kg]);
#pragma unroll
    for (int n = 0; n < 4; ++n)
      bfr[n] = *reinterpret_cast<const bf16x8*>(&sB[(wc * 64 + n * 16 + fr) * 32 + kg]);
#pragma unroll
    for (int m = 0; m < 4; ++m)
#pragma unroll
      for (int n = 0; n < 4; ++n)
        acc[m][n] = __builtin_amdgcn_mfma_f32_16x16x32_bf16(af[m], bfr[n], acc[m][n], 0, 0, 0);
    __syncthreads();  // before restaging
  }

  // epilogue: C/D layout col=lane&15, row=(lane>>4)*4+j  [m89-verified]
  const int fr = lane & 15, rg = (lane >> 4) * 4;
  unsigned short* Cb = reinterpret_cast<unsigned short*>(Cv) + (size_t)bz * (size_t)strideC;
  float* Cf = reinterpret_cast<float*>(Cv) + (size_t)bz * (size_t)strideC;
#pragma unroll
  for (int m = 0; m < 4; ++m) {
    int r0 = rowBase + wr * 64 + m * 16 + rg;
#pragma unroll
    for (int n = 0; n < 4; ++n) {
      int cidx = colBase + wc * 64 + n * 16 + fr;
      float bv = 0.0f;
      if (HAS_BIAS) bv = bias[cidx];
#pragma unroll
      for (int j = 0; j < 4; ++j) {
        float v = acc[m][n][j] * alpha + bv;
        if (OUT_BF16)
          Cb[(size_t)(r0 + j) * ldc + cidx] = f2bf(v);
        else
          Cf[(size_t)(r0 + j) * ldc + cidx] = v;
      }
    }
  }
}

// --------------------------- V transpose -----------------------------------
// Vt[b][d][s] = qkv[(b*2048+s)*3072 + 2048 + d]
__global__ void transpose_v(const unsigned short* __restrict__ qkv,
                            unsigned short* __restrict__ vt) {
  __shared__ unsigned short tile[32][33];
  const int b = blockIdx.z;
  const int d0 = blockIdx.x * 32;
  const int s0 = blockIdx.y * 32;
  const int tx = threadIdx.x, ty = threadIdx.y;  // 32 x 8
#pragma unroll
  for (int i = 0; i < 32; i += 8)
    tile[ty + i][tx] =
        qkv[(size_t)(b * 2048 + s0 + ty + i) * 3072 + 2048 + d0 + tx];
  __syncthreads();
#pragma unroll
  for (int i = 0; i < 32; i += 8)
    vt[((size_t)b * 1024 + d0 + ty + i) * 2048 + s0 + tx] = tile[tx][ty + i];
}

// --------------------------- row softmax (in place, bf16) ------------------
__global__ __launch_bounds__(256) void softmax_rows(unsigned short* __restrict__ s) {
  __shared__ float red[8];
  const size_t row = blockIdx.x;
  unsigned short* p = s + row * 2048;
  const int tid = threadIdx.x;

  ushort4 u0 = *reinterpret_cast<const ushort4*>(p + tid * 8);
  ushort4 u1 = *reinterpret_cast<const ushort4*>(p + tid * 8 + 4);
  float v[8];
  v[0] = bf2f(u0.x); v[1] = bf2f(u0.y); v[2] = bf2f(u0.z); v[3] = bf2f(u0.w);
  v[4] = bf2f(u1.x); v[5] = bf2f(u1.y); v[6] = bf2f(u1.z); v[7] = bf2f(u1.w);

  float mx = v[0];
#pragma unroll
  for (int j = 1; j < 8; ++j) mx = fmaxf(mx, v[j]);
#pragma unroll
  for (int off = 32; off; off >>= 1) mx = fmaxf(mx, __shfl_xor(mx, off));
  if ((tid & 63) == 0) red[tid >> 6] = mx;
  __syncthreads();
  mx = fmaxf(fmaxf(red[0], red[1]), fmaxf(red[2], red[3]));

  float e[8], sum = 0.0f;
#pragma unroll
  for (int j = 0; j < 8; ++j) { e[j] = __expf(v[j] - mx); sum += e[j]; }
#pragma unroll
  for (int off = 32; off; off >>= 1) sum += __shfl_xor(sum, off);
  if ((tid & 63) == 0) red[4 + (tid >> 6)] = sum;
  __syncthreads();
  sum = red[4] + red[5] + red[6] + red[7];
  const float inv = 1.0f / sum;

  ushort4 o0, o1;
  o0.x = f2bf(e[0] * inv); o0.y = f2bf(e[1] * inv);
  o0.z = f2bf(e[2] * inv); o0.w = f2bf(e[3] * inv);
  o1.x = f2bf(e[4] * inv); o1.y = f2bf(e[5] * inv);
  o1.z = f2bf(e[6] * inv); o1.w = f2bf(e[7] * inv);
  *reinterpret_cast<ushort4*>(p + tid * 8) = o0;
  *reinterpret_cast<ushort4*>(p + tid * 8 + 4) = o1;
}

// ---------------------------------------------------------------------------
extern "C" void kernel_launch(void* const* d_in, const int* in_sizes, int n_in,
                              void* d_out, int out_size, void* d_ws, size_t ws_size,
                              hipStream_t stream) {
  const float* x     = (const float*)d_in[0];   // [4,2048,1024]
  const float* Wqkv  = (const float*)d_in[1];   // [3072,1024]
  const float* bqkv  = (const float*)d_in[2];   // [3072]
  const float* Wproj = (const float*)d_in[3];   // [1024,1024]
  const float* bproj = (const float*)d_in[4];   // [1024]
  float* out = (float*)d_out;

  char* ws = (char*)d_ws;
  // workspace layout (bytes)
  unsigned short* qkv  = (unsigned short*)(ws + 0);          // 8192x3072 bf16 (50.3MB)
  unsigned short* xatt = (unsigned short*)(ws + 50331648);   // 8192x1024 bf16: x_bf16 then attn_out (16.8MB)
  unsigned short* wq   = (unsigned short*)(ws + 67108864);   // 3072x1024 bf16 (6.3MB)
  unsigned short* wp   = (unsigned short*)(ws + 73400320);   // 1024x1024 bf16 (2.1MB)
  unsigned short* vt   = (unsigned short*)(ws + 75497472);   // 4x1024x2048 bf16 (16.8MB)
  unsigned short* sc   = (unsigned short*)(ws + 92274688);   // 4x2048x2048 bf16 (33.6MB)
  // total 125829120 bytes

  dim3 blk(256);

  // 1. casts
  cvt_f32_bf16<<<2048, blk, 0, stream>>>(x, xatt, 8192 * 1024);
  cvt_f32_bf16<<<1024, blk, 0, stream>>>(Wqkv, wq, 3072 * 1024);
  cvt_f32_bf16<<<512, blk, 0, stream>>>(Wproj, wp, 1024 * 1024);

  // 2. QKV projection: [8192,3072] = x @ Wqkv^T + b
  gemm_nt<true, true><<<dim3(24, 64, 1), blk, 0, stream>>>(
      xatt, wq, qkv, bqkv, 8192, 3072, 1024, 1024, 1024, 3072, 0, 0, 0, 1.0f);

  // 3. V transpose -> Vt[b][d][s]
  transpose_v<<<dim3(32, 64, 4), dim3(32, 8), 0, stream>>>(qkv, vt);

  // 4. scores = Q @ K^T / 32  (per batch), bf16 out
  gemm_nt<true, false><<<dim3(16, 16, 4), blk, 0, stream>>>(
      qkv, qkv + 1024, sc, nullptr, 2048, 2048, 1024, 3072, 3072, 2048,
      2048LL * 3072, 2048LL * 3072, 2048LL * 2048, 0.03125f);

  // 5. softmax rows in place
  softmax_rows<<<8192, blk, 0, stream>>>(sc);

  // 6. attn_out = P @ V  (NT vs Vt), bf16 out (reuses x_bf16 region)
  gemm_nt<true, false><<<dim3(8, 16, 4), blk, 0, stream>>>(
      sc, vt, xatt, nullptr, 2048, 1024, 2048, 2048, 2048, 1024,
      2048LL * 2048, 1024LL * 2048, 2048LL * 1024, 1.0f);

  // 7. out = attn_out @ Wproj^T + b_proj, fp32 out
  gemm_nt<false, true><<<dim3(8, 64, 1), blk, 0, stream>>>(
      xatt, wp, out, bproj, 8192, 1024, 1024, 1024, 1024, 1024, 0, 0, 0, 1.0f);
}

// Round 2
// 231.492 us; speedup vs baseline: 1.1427x; 1.1427x over previous
//
#include <hip/hip_runtime.h>
#include <stdint.h>
#include <stddef.h>

// ---------------------------------------------------------------------------
// AttentionLayer: x[4,2048,1024] f32, W_qkv[3072,1024], b_qkv[3072],
//                 W_proj[1024,1024], b_proj[1024]  -> out[4,2048,1024] f32
// bf16 MFMA GEMMs, 256x256 8-phase schedule (T1+T2+T3+T4+T5), NT form.
// ---------------------------------------------------------------------------

typedef __attribute__((ext_vector_type(8))) short bf16x8;
typedef __attribute__((ext_vector_type(4))) float f32x4;

__device__ __forceinline__ unsigned short f2bf(float f) {
  unsigned u = __float_as_uint(f);
  u += 0x7fffu + ((u >> 16) & 1u);   // round-to-nearest-even
  return (unsigned short)(u >> 16);
}
__device__ __forceinline__ float bf2f(unsigned short h) {
  return __uint_as_float(((unsigned)h) << 16);
}

typedef const __attribute__((address_space(1))) void* gas_ptr;
typedef __attribute__((address_space(3))) void* las_ptr;

__device__ __forceinline__ void gload_lds16(const void* g, void* l) {
  __builtin_amdgcn_global_load_lds((gas_ptr)(uintptr_t)g,
                                   (las_ptr)(uint32_t)(uintptr_t)l, 16, 0, 0);
}

__device__ __forceinline__ f32x4 mfma16(bf16x8 a, bf16x8 b, f32x4 c) {
  return __builtin_amdgcn_mfma_f32_16x16x32_bf16(a, b, c, 0, 0, 0);
}

// --------------------------- fp32 -> bf16 cast -----------------------------
__global__ __launch_bounds__(256) void cvt_f32_bf16(
    const float* __restrict__ in, unsigned short* __restrict__ out, int n) {
  int i = (blockIdx.x * blockDim.x + threadIdx.x) * 4;
  int stride = gridDim.x * blockDim.x * 4;
  for (; i < n; i += stride) {
    float4 v = *reinterpret_cast<const float4*>(in + i);
    ushort4 o;
    o.x = f2bf(v.x); o.y = f2bf(v.y); o.z = f2bf(v.z); o.w = f2bf(v.w);
    *reinterpret_cast<ushort4*>(out + i) = o;
  }
}

// ---------------------- 256x256 8-phase staging helpers --------------------
// LDS A tile: storage row sr = h*128 + wr*64 + r  <-> logical row wr*128+h*64+r
// LDS B tile: storage row sc = h*128 + wc*32 + c  <-> logical col wc*64+h*32+c
// Swizzle: element_idx ^= (storage_row & 7) << 3  (16B groups), applied on
// the READ side; staging pre-swizzles the per-lane GLOBAL source column so
// global_load_lds's linear LDS write lands data at the swizzled position.

__device__ __forceinline__ void stage_A(const unsigned short* __restrict__ Ap,
                                        int lda, unsigned short* sAb, int h,
                                        int tid) {
  const int wid = tid >> 6, l = tid & 63;
  const int rsub = (l >> 3);                       // 0..7 within wave's 8 rows
  const int cg = (((l & 7) ^ rsub) * 8);           // pre-swizzled source col
#pragma unroll
  for (int c = 0; c < 2; ++c) {
    int logical_row = c * 128 + h * 64 + wid * 8 + rsub;
    gload_lds16(Ap + (size_t)logical_row * lda + cg,
                sAb + h * 8192 + c * 4096 + wid * 512);
  }
}

__device__ __forceinline__ void stage_B(const unsigned short* __restrict__ Bp,
                                        int ldb, unsigned short* sBb, int h,
                                        int tid) {
  const int wid = tid >> 6, l = tid & 63;
  const int rsub = (l >> 3);
  const int cg = (((l & 7) ^ rsub) * 8);
  const int ccol = (wid & 3) * 8 + rsub;
#pragma unroll
  for (int c = 0; c < 2; ++c) {
    int wcs = c * 2 + (wid >> 2);
    int logical_col = wcs * 64 + h * 32 + ccol;
    gload_lds16(Bp + (size_t)logical_col * ldb + cg,
                sBb + h * 8192 + c * 4096 + wid * 512);
  }
}

// --------------------------- 256x256 NT bf16 GEMM --------------------------
// C[m,n] = alpha * sum_k A[m,k]*B[n,k]  (+ bias[n]); batched via blockIdx.z.
// 512 threads = 8 waves (2M x 4N); per-wave 128x64 out; BK=64; 2x64KB LDS dbuf.
template <bool OUT_BF16, bool HAS_BIAS>
__global__ __launch_bounds__(512, 2) void gemm256(
    const unsigned short* __restrict__ A, const unsigned short* __restrict__ B,
    void* __restrict__ Cv, const float* __restrict__ bias,
    int M, int N, int K, int lda, int ldb, int ldc,
    long long strideA, long long strideB, long long strideC, float alpha) {
  __shared__ unsigned short sA[2][256 * 64];
  __shared__ unsigned short sB[2][256 * 64];

  const int bz = blockIdx.z;
  const int gx = gridDim.x;
  int lin = blockIdx.y * gx + blockIdx.x;
  const int nwg = gx * gridDim.y;
  if ((nwg & 7) == 0) {  // bijective XCD swizzle (T1)
    const int q = nwg >> 3;
    lin = (lin & 7) * q + (lin >> 3);
  }
  const int bx = lin % gx, by = lin / gx;
  const int rowBase = by * 256;
  const int colBase = bx * 256;

  const unsigned short* Ap = A + (size_t)bz * (size_t)strideA + (size_t)rowBase * lda;
  const unsigned short* Bp = B + (size_t)bz * (size_t)strideB + (size_t)colBase * ldb;

  const int tid = threadIdx.x;
  const int wid = tid >> 6;
  const int lane = tid & 63;
  const int wr = wid >> 2;        // 0..1
  const int wc = wid & 3;         // 0..3
  const int fr = lane & 15;
  const int kg = (lane >> 4) * 8;
  const int swz = (fr & 7) << 3;
  const int col0 = kg ^ swz;
  const int col1 = (32 + kg) ^ swz;

  const int nt = K >> 6;  // K-tiles of 64

  f32x4 acc[8][4] = {};
  bf16x8 af[4][2], bf0[2][2], bf1[2][2];

  // ---- prologue: stage t0 fully + t1 {A0,B0,B1}; counted wait ----
  stage_A(Ap, lda, sA[0], 0, tid);
  stage_B(Bp, ldb, sB[0], 0, tid);
  stage_B(Bp, ldb, sB[0], 1, tid);
  stage_A(Ap, lda, sA[0], 1, tid);
  if (nt > 1) {
    stage_A(Ap + 64, lda, sA[1], 0, tid);
    stage_B(Bp + 64, ldb, sB[1], 0, tid);
    stage_B(Bp + 64, ldb, sB[1], 1, tid);
    asm volatile("s_waitcnt vmcnt(6)" ::: "memory");
  } else {
    asm volatile("s_waitcnt vmcnt(0)" ::: "memory");
  }
  __builtin_amdgcn_sched_barrier(0);
  __builtin_amdgcn_s_barrier();

  for (int t = 0; t < nt; ++t) {
    const int cur = t & 1;
    const unsigned short* sAc = sA[cur];
    const unsigned short* sBc = sB[cur];

    // ---- phase 1: read A.h0 (8) + B.h0 (4); MFMA m0-3 x n0-1 ----
#pragma unroll
    for (int m = 0; m < 4; ++m) {
      int srow = wr * 64 + m * 16 + fr;
      af[m][0] = *(const bf16x8*)&sAc[srow * 64 + col0];
      af[m][1] = *(const bf16x8*)&sAc[srow * 64 + col1];
    }
#pragma unroll
    for (int n = 0; n < 2; ++n) {
      int scol = wc * 32 + n * 16 + fr;
      bf0[n][0] = *(const bf16x8*)&sBc[scol * 64 + col0];
      bf0[n][1] = *(const bf16x8*)&sBc[scol * 64 + col1];
    }
    if (t + 1 < nt) stage_A(Ap + (size_t)(t + 1) * 64, lda, sA[cur ^ 1], 1, tid);
    __builtin_amdgcn_s_barrier();
    asm volatile("s_waitcnt lgkmcnt(0)" ::: "memory");
    __builtin_amdgcn_sched_barrier(0);
    __builtin_amdgcn_s_setprio(1);
#pragma unroll
    for (int m = 0; m < 4; ++m)
#pragma unroll
      for (int n = 0; n < 2; ++n) {
        acc[m][n] = mfma16(af[m][0], bf0[n][0], acc[m][n]);
        acc[m][n] = mfma16(af[m][1], bf0[n][1], acc[m][n]);
      }
    __builtin_amdgcn_s_setprio(0);
    __builtin_amdgcn_sched_barrier(0);
    __builtin_amdgcn_s_barrier();

    // ---- phase 2: read B.h1 (4); MFMA m0-3 x n2-3 ----
#pragma unroll
    for (int n = 0; n < 2; ++n) {
      int scol = 128 + wc * 32 + n * 16 + fr;
      bf1[n][0] = *(const bf16x8*)&sBc[scol * 64 + col0];
      bf1[n][1] = *(const bf16x8*)&sBc[scol * 64 + col1];
    }
    if (t + 2 < nt) stage_A(Ap + (size_t)(t + 2) * 64, lda, sA[cur], 0, tid);
    __builtin_amdgcn_s_barrier();
    asm volatile("s_waitcnt lgkmcnt(0)" ::: "memory");
    __builtin_amdgcn_sched_barrier(0);
    __builtin_amdgcn_s_setprio(1);
#pragma unroll
    for (int m = 0; m < 4; ++m)
#pragma unroll
      for (int n = 0; n < 2; ++n) {
        acc[m][2 + n] = mfma16(af[m][0], bf1[n][0], acc[m][2 + n]);
        acc[m][2 + n] = mfma16(af[m][1], bf1[n][1], acc[m][2 + n]);
      }
    __builtin_amdgcn_s_setprio(0);
    __builtin_amdgcn_sched_barrier(0);
    __builtin_amdgcn_s_barrier();

    // ---- phase 3: read A.h1 (8); MFMA m4-7 x n2-3 ----
#pragma unroll
    for (int m = 0; m < 4; ++m) {
      int srow = 128 + wr * 64 + m * 16 + fr;
      af[m][0] = *(const bf16x8*)&sAc[srow * 64 + col0];
      af[m][1] = *(const bf16x8*)&sAc[srow * 64 + col1];
    }
    if (t + 2 < nt) stage_B(Bp + (size_t)(t + 2) * 64, ldb, sB[cur], 0, tid);
    __builtin_amdgcn_s_barrier();
    asm volatile("s_waitcnt lgkmcnt(0)" ::: "memory");
    __builtin_amdgcn_sched_barrier(0);
    __builtin_amdgcn_s_setprio(1);
#pragma unroll
    for (int m = 0; m < 4; ++m)
#pragma unroll
      for (int n = 0; n < 2; ++n) {
        acc[4 + m][2 + n] = mfma16(af[m][0], bf1[n][0], acc[4 + m][2 + n]);
        acc[4 + m][2 + n] = mfma16(af[m][1], bf1[n][1], acc[4 + m][2 + n]);
      }
    __builtin_amdgcn_s_setprio(0);
    __builtin_amdgcn_sched_barrier(0);
    __builtin_amdgcn_s_barrier();

    // ---- phase 4: no reads; MFMA m4-7 x n0-1; counted vmcnt ----
    if (t + 2 < nt) stage_B(Bp + (size_t)(t + 2) * 64, ldb, sB[cur], 1, tid);
    __builtin_amdgcn_s_setprio(1);
#pragma unroll
    for (int m = 0; m < 4; ++m)
#pragma unroll
      for (int n = 0; n < 2; ++n) {
        acc[4 + m][n] = mfma16(af[m][0], bf0[n][0], acc[4 + m][n]);
        acc[4 + m][n] = mfma16(af[m][1], bf0[n][1], acc[4 + m][n]);
      }
    __builtin_amdgcn_s_setprio(0);
    __builtin_amdgcn_sched_barrier(0);
    if (t + 2 < nt) {
      asm volatile("s_waitcnt vmcnt(6)" ::: "memory");
    } else if (t + 1 < nt) {
      asm volatile("s_waitcnt vmcnt(0)" ::: "memory");
    }
    __builtin_amdgcn_sched_barrier(0);
    __builtin_amdgcn_s_barrier();
  }

  // ---- epilogue: C/D layout col=lane&15, row=(lane>>4)*4+j ----
  unsigned short* Cb = reinterpret_cast<unsigned short*>(Cv) + (size_t)bz * (size_t)strideC;
  float* Cf = reinterpret_cast<float*>(Cv) + (size_t)bz * (size_t)strideC;
  const int rg = (lane >> 4) * 4;
#pragma unroll
  for (int m = 0; m < 8; ++m) {
    int r0 = rowBase + wr * 128 + m * 16 + rg;
#pragma unroll
    for (int n = 0; n < 4; ++n) {
      int cidx = colBase + wc * 64 + n * 16 + fr;
      float bv = 0.0f;
      if (HAS_BIAS) bv = bias[cidx];
#pragma unroll
      for (int j = 0; j < 4; ++j) {
        float v = acc[m][n][j] * alpha + bv;
        if (OUT_BF16)
          Cb[(size_t)(r0 + j) * ldc + cidx] = f2bf(v);
        else
          Cf[(size_t)(r0 + j) * ldc + cidx] = v;
      }
    }
  }
}

// --------------------------- V transpose -----------------------------------
__global__ void transpose_v(const unsigned short* __restrict__ qkv,
                            unsigned short* __restrict__ vt) {
  __shared__ unsigned short tile[32][33];
  const int b = blockIdx.z;
  const int d0 = blockIdx.x * 32;
  const int s0 = blockIdx.y * 32;
  const int tx = threadIdx.x, ty = threadIdx.y;  // 32 x 8
#pragma unroll
  for (int i = 0; i < 32; i += 8)
    tile[ty + i][tx] =
        qkv[(size_t)(b * 2048 + s0 + ty + i) * 3072 + 2048 + d0 + tx];
  __syncthreads();
#pragma unroll
  for (int i = 0; i < 32; i += 8)
    vt[((size_t)b * 1024 + d0 + ty + i) * 2048 + s0 + tx] = tile[tx][ty + i];
}

// --------------------------- row softmax (in place, bf16) ------------------
__global__ __launch_bounds__(256) void softmax_rows(unsigned short* __restrict__ s) {
  __shared__ float red[8];
  const size_t row = blockIdx.x;
  unsigned short* p = s + row * 2048;
  const int tid = threadIdx.x;

  ushort4 u0 = *reinterpret_cast<const ushort4*>(p + tid * 8);
  ushort4 u1 = *reinterpret_cast<const ushort4*>(p + tid * 8 + 4);
  float v[8];
  v[0] = bf2f(u0.x); v[1] = bf2f(u0.y); v[2] = bf2f(u0.z); v[3] = bf2f(u0.w);
  v[4] = bf2f(u1.x); v[5] = bf2f(u1.y); v[6] = bf2f(u1.z); v[7] = bf2f(u1.w);

  float mx = v[0];
#pragma unroll
  for (int j = 1; j < 8; ++j) mx = fmaxf(mx, v[j]);
#pragma unroll
  for (int off = 32; off; off >>= 1) mx = fmaxf(mx, __shfl_xor(mx, off));
  if ((tid & 63) == 0) red[tid >> 6] = mx;
  __syncthreads();
  mx = fmaxf(fmaxf(red[0], red[1]), fmaxf(red[2], red[3]));

  float e[8], sum = 0.0f;
#pragma unroll
  for (int j = 0; j < 8; ++j) { e[j] = __expf(v[j] - mx); sum += e[j]; }
#pragma unroll
  for (int off = 32; off; off >>= 1) sum += __shfl_xor(sum, off);
  if ((tid & 63) == 0) red[4 + (tid >> 6)] = sum;
  __syncthreads();
  sum = red[4] + red[5] + red[6] + red[7];
  const float inv = 1.0f / sum;

  ushort4 o0, o1;
  o0.x = f2bf(e[0] * inv); o0.y = f2bf(e[1] * inv);
  o0.z = f2bf(e[2] * inv); o0.w = f2bf(e[3] * inv);
  o1.x = f2bf(e[4] * inv); o1.y = f2bf(e[5] * inv);
  o1.z = f2bf(e[6] * inv); o1.w = f2bf(e[7] * inv);
  *reinterpret_cast<ushort4*>(p + tid * 8) = o0;
  *reinterpret_cast<ushort4*>(p + tid * 8 + 4) = o1;
}

// ---------------------------------------------------------------------------
extern "C" void kernel_launch(void* const* d_in, const int* in_sizes, int n_in,
                              void* d_out, int out_size, void* d_ws, size_t ws_size,
                              hipStream_t stream) {
  const float* x     = (const float*)d_in[0];
  const float* Wqkv  = (const float*)d_in[1];
  const float* bqkv  = (const float*)d_in[2];
  const float* Wproj = (const float*)d_in[3];
  const float* bproj = (const float*)d_in[4];
  float* out = (float*)d_out;

  char* ws = (char*)d_ws;
  unsigned short* qkv  = (unsigned short*)(ws + 0);          // 8192x3072 bf16
  unsigned short* xatt = (unsigned short*)(ws + 50331648);   // 8192x1024 bf16
  unsigned short* wq   = (unsigned short*)(ws + 67108864);   // 3072x1024 bf16
  unsigned short* wp   = (unsigned short*)(ws + 73400320);   // 1024x1024 bf16
  unsigned short* vt   = (unsigned short*)(ws + 75497472);   // 4x1024x2048 bf16
  unsigned short* sc   = (unsigned short*)(ws + 92274688);   // 4x2048x2048 bf16

  dim3 blk256(256), blk512(512);

  // 1. casts
  cvt_f32_bf16<<<2048, blk256, 0, stream>>>(x, xatt, 8192 * 1024);
  cvt_f32_bf16<<<1024, blk256, 0, stream>>>(Wqkv, wq, 3072 * 1024);
  cvt_f32_bf16<<<512, blk256, 0, stream>>>(Wproj, wp, 1024 * 1024);

  // 2. QKV projection: [8192,3072] = x @ Wqkv^T + b   (grid 12x32 = 384)
  gemm256<true, true><<<dim3(12, 32, 1), blk512, 0, stream>>>(
      xatt, wq, qkv, bqkv, 8192, 3072, 1024, 1024, 1024, 3072, 0, 0, 0, 1.0f);

  // 3. V transpose -> Vt[b][d][s]
  transpose_v<<<dim3(32, 64, 4), dim3(32, 8), 0, stream>>>(qkv, vt);

  // 4. scores = Q @ K^T / 32  (grid 8x8x4 = 256)
  gemm256<true, false><<<dim3(8, 8, 4), blk512, 0, stream>>>(
      qkv, qkv + 1024, sc, nullptr, 2048, 2048, 1024, 3072, 3072, 2048,
      2048LL * 3072, 2048LL * 3072, 2048LL * 2048, 0.03125f);

  // 5. softmax rows in place
  softmax_rows<<<8192, blk256, 0, stream>>>(sc);

  // 6. attn_out = P @ Vt  (grid 4x8x4 = 128)
  gemm256<true, false><<<dim3(4, 8, 4), blk512, 0, stream>>>(
      sc, vt, xatt, nullptr, 2048, 1024, 2048, 2048, 2048, 1024,
      2048LL * 2048, 1024LL * 2048, 2048LL * 1024, 1.0f);

  // 7. out = attn_out @ Wproj^T + b_proj  (grid 4x32 = 128)
  gemm256<false, true><<<dim3(4, 32, 1), blk512, 0, stream>>>(
      xatt, wp, out, bproj, 8192, 1024, 1024, 1024, 1024, 1024, 0, 0, 0, 1.0f);
}

// Round 3
// 202.032 us; speedup vs baseline: 1.3093x; 1.1458x over previous
//
#include <hip/hip_runtime.h>
#include <stdint.h>
#include <stddef.h>

// ---------------------------------------------------------------------------
// AttentionLayer: x[4,2048,1024] f32, W_qkv[3072,1024], b_qkv[3072],
//                 W_proj[1024,1024], b_proj[1024]  -> out[4,2048,1024] f32
// bf16 MFMA GEMMs, 8-phase-style schedules (T1+T2+T3+T4+T5), NT form.
// gemm256: 256x256 tile (used where grid is exactly 256 blocks: QK^T).
// gemm_bm128: 128x256 tile (QKV: 768 blocks, PV: 256, proj: 256 -> no tails).
// ---------------------------------------------------------------------------

typedef __attribute__((ext_vector_type(8))) short bf16x8;
typedef __attribute__((ext_vector_type(4))) float f32x4;

__device__ __forceinline__ unsigned short f2bf(float f) {
  unsigned u = __float_as_uint(f);
  u += 0x7fffu + ((u >> 16) & 1u);
  return (unsigned short)(u >> 16);
}
__device__ __forceinline__ float bf2f(unsigned short h) {
  return __uint_as_float(((unsigned)h) << 16);
}

typedef const __attribute__((address_space(1))) void* gas_ptr;
typedef __attribute__((address_space(3))) void* las_ptr;

__device__ __forceinline__ void gload_lds16(const void* g, void* l) {
  __builtin_amdgcn_global_load_lds((gas_ptr)(uintptr_t)g,
                                   (las_ptr)(uint32_t)(uintptr_t)l, 16, 0, 0);
}

__device__ __forceinline__ f32x4 mfma16(bf16x8 a, bf16x8 b, f32x4 c) {
  return __builtin_amdgcn_mfma_f32_16x16x32_bf16(a, b, c, 0, 0, 0);
}

// --------------------------- fp32 -> bf16 cast -----------------------------
__global__ __launch_bounds__(256) void cvt_f32_bf16(
    const float* __restrict__ in, unsigned short* __restrict__ out, int n) {
  int i = (blockIdx.x * blockDim.x + threadIdx.x) * 4;
  int stride = gridDim.x * blockDim.x * 4;
  for (; i < n; i += stride) {
    float4 v = *reinterpret_cast<const float4*>(in + i);
    ushort4 o;
    o.x = f2bf(v.x); o.y = f2bf(v.y); o.z = f2bf(v.z); o.w = f2bf(v.w);
    *reinterpret_cast<ushort4*>(out + i) = o;
  }
}

// ======================= 256x256 kernel (QK^T) =============================
__device__ __forceinline__ void stage_A(const unsigned short* __restrict__ Ap,
                                        int lda, unsigned short* sAb, int h,
                                        int tid) {
  const int wid = tid >> 6, l = tid & 63;
  const int rsub = (l >> 3);
  const int cg = (((l & 7) ^ rsub) * 8);
#pragma unroll
  for (int c = 0; c < 2; ++c) {
    int logical_row = c * 128 + h * 64 + wid * 8 + rsub;
    gload_lds16(Ap + (size_t)logical_row * lda + cg,
                sAb + h * 8192 + c * 4096 + wid * 512);
  }
}

__device__ __forceinline__ void stage_B(const unsigned short* __restrict__ Bp,
                                        int ldb, unsigned short* sBb, int h,
                                        int tid) {
  const int wid = tid >> 6, l = tid & 63;
  const int rsub = (l >> 3);
  const int cg = (((l & 7) ^ rsub) * 8);
  const int ccol = (wid & 3) * 8 + rsub;
#pragma unroll
  for (int c = 0; c < 2; ++c) {
    int wcs = c * 2 + (wid >> 2);
    int logical_col = wcs * 64 + h * 32 + ccol;
    gload_lds16(Bp + (size_t)logical_col * ldb + cg,
                sBb + h * 8192 + c * 4096 + wid * 512);
  }
}

template <bool OUT_BF16, bool HAS_BIAS>
__global__ __launch_bounds__(512, 2) void gemm256(
    const unsigned short* __restrict__ A, const unsigned short* __restrict__ B,
    void* __restrict__ Cv, const float* __restrict__ bias,
    int M, int N, int K, int lda, int ldb, int ldc,
    long long strideA, long long strideB, long long strideC, float alpha) {
  __shared__ unsigned short sA[2][256 * 64];
  __shared__ unsigned short sB[2][256 * 64];

  const int bz = blockIdx.z;
  const int gx = gridDim.x;
  int lin = blockIdx.y * gx + blockIdx.x;
  const int nwg = gx * gridDim.y;
  if ((nwg & 7) == 0) {
    const int q = nwg >> 3;
    lin = (lin & 7) * q + (lin >> 3);
  }
  const int bx = lin % gx, by = lin / gx;
  const int rowBase = by * 256;
  const int colBase = bx * 256;

  const unsigned short* Ap = A + (size_t)bz * (size_t)strideA + (size_t)rowBase * lda;
  const unsigned short* Bp = B + (size_t)bz * (size_t)strideB + (size_t)colBase * ldb;

  const int tid = threadIdx.x;
  const int wid = tid >> 6;
  const int lane = tid & 63;
  const int wr = wid >> 2;
  const int wc = wid & 3;
  const int fr = lane & 15;
  const int kg = (lane >> 4) * 8;
  const int swz = (fr & 7) << 3;
  const int col0 = kg ^ swz;
  const int col1 = (32 + kg) ^ swz;

  const int nt = K >> 6;

  f32x4 acc[8][4] = {};
  bf16x8 af[4][2], bf0[2][2], bf1[2][2];

  stage_A(Ap, lda, sA[0], 0, tid);
  stage_B(Bp, ldb, sB[0], 0, tid);
  stage_B(Bp, ldb, sB[0], 1, tid);
  stage_A(Ap, lda, sA[0], 1, tid);
  if (nt > 1) {
    stage_A(Ap + 64, lda, sA[1], 0, tid);
    stage_B(Bp + 64, ldb, sB[1], 0, tid);
    stage_B(Bp + 64, ldb, sB[1], 1, tid);
    asm volatile("s_waitcnt vmcnt(6)" ::: "memory");
  } else {
    asm volatile("s_waitcnt vmcnt(0)" ::: "memory");
  }
  __builtin_amdgcn_sched_barrier(0);
  __builtin_amdgcn_s_barrier();

  for (int t = 0; t < nt; ++t) {
    const int cur = t & 1;
    const unsigned short* sAc = sA[cur];
    const unsigned short* sBc = sB[cur];

#pragma unroll
    for (int m = 0; m < 4; ++m) {
      int srow = wr * 64 + m * 16 + fr;
      af[m][0] = *(const bf16x8*)&sAc[srow * 64 + col0];
      af[m][1] = *(const bf16x8*)&sAc[srow * 64 + col1];
    }
#pragma unroll
    for (int n = 0; n < 2; ++n) {
      int scol = wc * 32 + n * 16 + fr;
      bf0[n][0] = *(const bf16x8*)&sBc[scol * 64 + col0];
      bf0[n][1] = *(const bf16x8*)&sBc[scol * 64 + col1];
    }
    if (t + 1 < nt) stage_A(Ap + (size_t)(t + 1) * 64, lda, sA[cur ^ 1], 1, tid);
    __builtin_amdgcn_s_barrier();
    asm volatile("s_waitcnt lgkmcnt(0)" ::: "memory");
    __builtin_amdgcn_sched_barrier(0);
    __builtin_amdgcn_s_setprio(1);
#pragma unroll
    for (int m = 0; m < 4; ++m)
#pragma unroll
      for (int n = 0; n < 2; ++n) {
        acc[m][n] = mfma16(af[m][0], bf0[n][0], acc[m][n]);
        acc[m][n] = mfma16(af[m][1], bf0[n][1], acc[m][n]);
      }
    __builtin_amdgcn_s_setprio(0);
    __builtin_amdgcn_sched_barrier(0);
    __builtin_amdgcn_s_barrier();

#pragma unroll
    for (int n = 0; n < 2; ++n) {
      int scol = 128 + wc * 32 + n * 16 + fr;
      bf1[n][0] = *(const bf16x8*)&sBc[scol * 64 + col0];
      bf1[n][1] = *(const bf16x8*)&sBc[scol * 64 + col1];
    }
    if (t + 2 < nt) stage_A(Ap + (size_t)(t + 2) * 64, lda, sA[cur], 0, tid);
    __builtin_amdgcn_s_barrier();
    asm volatile("s_waitcnt lgkmcnt(0)" ::: "memory");
    __builtin_amdgcn_sched_barrier(0);
    __builtin_amdgcn_s_setprio(1);
#pragma unroll
    for (int m = 0; m < 4; ++m)
#pragma unroll
      for (int n = 0; n < 2; ++n) {
        acc[m][2 + n] = mfma16(af[m][0], bf1[n][0], acc[m][2 + n]);
        acc[m][2 + n] = mfma16(af[m][1], bf1[n][1], acc[m][2 + n]);
      }
    __builtin_amdgcn_s_setprio(0);
    __builtin_amdgcn_sched_barrier(0);
    __builtin_amdgcn_s_barrier();

#pragma unroll
    for (int m = 0; m < 4; ++m) {
      int srow = 128 + wr * 64 + m * 16 + fr;
      af[m][0] = *(const bf16x8*)&sAc[srow * 64 + col0];
      af[m][1] = *(const bf16x8*)&sAc[srow * 64 + col1];
    }
    if (t + 2 < nt) stage_B(Bp + (size_t)(t + 2) * 64, ldb, sB[cur], 0, tid);
    __builtin_amdgcn_s_barrier();
    asm volatile("s_waitcnt lgkmcnt(0)" ::: "memory");
    __builtin_amdgcn_sched_barrier(0);
    __builtin_amdgcn_s_setprio(1);
#pragma unroll
    for (int m = 0; m < 4; ++m)
#pragma unroll
      for (int n = 0; n < 2; ++n) {
        acc[4 + m][2 + n] = mfma16(af[m][0], bf1[n][0], acc[4 + m][2 + n]);
        acc[4 + m][2 + n] = mfma16(af[m][1], bf1[n][1], acc[4 + m][2 + n]);
      }
    __builtin_amdgcn_s_setprio(0);
    __builtin_amdgcn_sched_barrier(0);
    __builtin_amdgcn_s_barrier();

    if (t + 2 < nt) stage_B(Bp + (size_t)(t + 2) * 64, ldb, sB[cur], 1, tid);
    __builtin_amdgcn_s_setprio(1);
#pragma unroll
    for (int m = 0; m < 4; ++m)
#pragma unroll
      for (int n = 0; n < 2; ++n) {
        acc[4 + m][n] = mfma16(af[m][0], bf0[n][0], acc[4 + m][n]);
        acc[4 + m][n] = mfma16(af[m][1], bf0[n][1], acc[4 + m][n]);
      }
    __builtin_amdgcn_s_setprio(0);
    __builtin_amdgcn_sched_barrier(0);
    if (t + 2 < nt) {
      asm volatile("s_waitcnt vmcnt(6)" ::: "memory");
    } else if (t + 1 < nt) {
      asm volatile("s_waitcnt vmcnt(0)" ::: "memory");
    }
    __builtin_amdgcn_sched_barrier(0);
    __builtin_amdgcn_s_barrier();
  }

  unsigned short* Cb = reinterpret_cast<unsigned short*>(Cv) + (size_t)bz * (size_t)strideC;
  float* Cf = reinterpret_cast<float*>(Cv) + (size_t)bz * (size_t)strideC;
  const int rg = (lane >> 4) * 4;
#pragma unroll
  for (int m = 0; m < 8; ++m) {
    int r0 = rowBase + wr * 128 + m * 16 + rg;
#pragma unroll
    for (int n = 0; n < 4; ++n) {
      int cidx = colBase + wc * 64 + n * 16 + fr;
      float bv = 0.0f;
      if (HAS_BIAS) bv = bias[cidx];
#pragma unroll
      for (int j = 0; j < 4; ++j) {
        float v = acc[m][n][j] * alpha + bv;
        if (OUT_BF16)
          Cb[(size_t)(r0 + j) * ldc + cidx] = f2bf(v);
        else
          Cf[(size_t)(r0 + j) * ldc + cidx] = v;
      }
    }
  }
}

// ======================= 128x256 kernel (QKV, PV, proj) ====================
// A tile 128x64 (16KB): storage row = h*64 + wid*8 + rsub (h = m-half),
//   logical row = (wid>>2)*64 + h*32 + (wid&3)*8 + rsub.
// B tile 256x64 (32KB): storage row = nh*128 + u*64 + wid*8 + rsub,
//   logical col = (u*2 + (wid>>2))*64 + nh*32 + (wid&3)*8 + rsub.
// Phases: ph1 {A.mh0,B.nh0} -> 8 MFMA; ph2 {A.mh1} -> 8; ph3 {B.nh1} -> 8;
//         ph4 regs-only -> 8.  Stages of t+2: ph2 A.h0, ph3 B.nh0(2),
//         ph4 A.h1 + B.nh1(2).  vmcnt(6) per tile.

__device__ __forceinline__ void stage_A128(const unsigned short* __restrict__ Ap,
                                           int lda, unsigned short* sAb, int h,
                                           int tid) {
  const int wid = tid >> 6, l = tid & 63;
  const int rsub = (l >> 3);
  const int cg = (((l & 7) ^ rsub) * 8);
  int logical_row = (wid >> 2) * 64 + h * 32 + (wid & 3) * 8 + rsub;
  gload_lds16(Ap + (size_t)logical_row * lda + cg, sAb + h * 4096 + wid * 512);
}

__device__ __forceinline__ void stage_B128(const unsigned short* __restrict__ Bp,
                                           int ldb, unsigned short* sBb, int nh,
                                           int tid) {
  const int wid = tid >> 6, l = tid & 63;
  const int rsub = (l >> 3);
  const int cg = (((l & 7) ^ rsub) * 8);
#pragma unroll
  for (int u = 0; u < 2; ++u) {
    int logical_col = (u * 2 + (wid >> 2)) * 64 + nh * 32 + (wid & 3) * 8 + rsub;
    gload_lds16(Bp + (size_t)logical_col * ldb + cg,
                sBb + nh * 8192 + u * 4096 + wid * 512);
  }
}

template <bool OUT_BF16, bool HAS_BIAS>
__global__ __launch_bounds__(512, 2) void gemm_bm128(
    const unsigned short* __restrict__ A, const unsigned short* __restrict__ B,
    void* __restrict__ Cv, const float* __restrict__ bias,
    int M, int N, int K, int lda, int ldb, int ldc,
    long long strideA, long long strideB, long long strideC, float alpha) {
  __shared__ unsigned short sA[2][128 * 64];
  __shared__ unsigned short sB[2][256 * 64];

  const int bz = blockIdx.z;
  const int gx = gridDim.x;
  int lin = blockIdx.y * gx + blockIdx.x;
  const int nwg = gx * gridDim.y;
  if ((nwg & 7) == 0) {
    const int q = nwg >> 3;
    lin = (lin & 7) * q + (lin >> 3);
  }
  const int bx = lin % gx, by = lin / gx;
  const int rowBase = by * 128;
  const int colBase = bx * 256;

  const unsigned short* Ap = A + (size_t)bz * (size_t)strideA + (size_t)rowBase * lda;
  const unsigned short* Bp = B + (size_t)bz * (size_t)strideB + (size_t)colBase * ldb;

  const int tid = threadIdx.x;
  const int wid = tid >> 6;
  const int lane = tid & 63;
  const int wr = wid >> 2;   // 0..1 -> 64-row half
  const int wc = wid & 3;    // 0..3 -> 64-col quarter
  const int fr = lane & 15;
  const int kg = (lane >> 4) * 8;
  const int swz = (fr & 7) << 3;
  const int col0 = kg ^ swz;
  const int col1 = (32 + kg) ^ swz;

  const int nt = K >> 6;

  f32x4 acc[4][4] = {};
  bf16x8 af[4][2], bfr[4][2];   // af[m][k], bfr[n][k]

  // prologue: stage t0 + t1 fully (6 gloads each)
  stage_A128(Ap, lda, sA[0], 0, tid);
  stage_A128(Ap, lda, sA[0], 1, tid);
  stage_B128(Bp, ldb, sB[0], 0, tid);
  stage_B128(Bp, ldb, sB[0], 1, tid);
  if (nt > 1) {
    stage_A128(Ap + 64, lda, sA[1], 0, tid);
    stage_A128(Ap + 64, lda, sA[1], 1, tid);
    stage_B128(Bp + 64, ldb, sB[1], 0, tid);
    stage_B128(Bp + 64, ldb, sB[1], 1, tid);
    asm volatile("s_waitcnt vmcnt(6)" ::: "memory");
  } else {
    asm volatile("s_waitcnt vmcnt(0)" ::: "memory");
  }
  __builtin_amdgcn_sched_barrier(0);
  __builtin_amdgcn_s_barrier();

  for (int t = 0; t < nt; ++t) {
    const int cur = t & 1;
    const unsigned short* sAc = sA[cur];
    const unsigned short* sBc = sB[cur];

    // ---- ph1: read A.mh0 (af[0..1]) + B.nh0 (bfr[0..1]); MFMA (m01)x(n01) ----
#pragma unroll
    for (int m = 0; m < 2; ++m) {
      int srow = wr * 32 + m * 16 + fr;             // h=0: storage rows 0..63
      af[m][0] = *(const bf16x8*)&sAc[srow * 64 + col0];
      af[m][1] = *(const bf16x8*)&sAc[srow * 64 + col1];
    }
#pragma unroll
    for (int n = 0; n < 2; ++n) {
      int srow = wc * 32 + n * 16 + fr;             // nh=0: storage rows 0..127
      bfr[n][0] = *(const bf16x8*)&sBc[srow * 64 + col0];
      bfr[n][1] = *(const bf16x8*)&sBc[srow * 64 + col1];
    }
    __builtin_amdgcn_s_barrier();
    asm volatile("s_waitcnt lgkmcnt(0)" ::: "memory");
    __builtin_amdgcn_sched_barrier(0);
    __builtin_amdgcn_s_setprio(1);
#pragma unroll
    for (int m = 0; m < 2; ++m)
#pragma unroll
      for (int n = 0; n < 2; ++n) {
        acc[m][n] = mfma16(af[m][0], bfr[n][0], acc[m][n]);
        acc[m][n] = mfma16(af[m][1], bfr[n][1], acc[m][n]);
      }
    __builtin_amdgcn_s_setprio(0);
    __builtin_amdgcn_sched_barrier(0);
    __builtin_amdgcn_s_barrier();

    // ---- ph2: read A.mh1 (af[2..3]); stage A.h0(t+2); MFMA (m23)x(n01) ----
#pragma unroll
    for (int m = 0; m < 2; ++m) {
      int srow = 64 + wr * 32 + m * 16 + fr;        // h=1: storage rows 64..127
      af[2 + m][0] = *(const bf16x8*)&sAc[srow * 64 + col0];
      af[2 + m][1] = *(const bf16x8*)&sAc[srow * 64 + col1];
    }
    if (t + 2 < nt) stage_A128(Ap + (size_t)(t + 2) * 64, lda, sA[cur], 0, tid);
    __builtin_amdgcn_s_barrier();
    asm volatile("s_waitcnt lgkmcnt(0)" ::: "memory");
    __builtin_amdgcn_sched_barrier(0);
    __builtin_amdgcn_s_setprio(1);
#pragma unroll
    for (int m = 0; m < 2; ++m)
#pragma unroll
      for (int n = 0; n < 2; ++n) {
        acc[2 + m][n] = mfma16(af[2 + m][0], bfr[n][0], acc[2 + m][n]);
        acc[2 + m][n] = mfma16(af[2 + m][1], bfr[n][1], acc[2 + m][n]);
      }
    __builtin_amdgcn_s_setprio(0);
    __builtin_amdgcn_sched_barrier(0);
    __builtin_amdgcn_s_barrier();

    // ---- ph3: read B.nh1 (bfr[2..3]); stage B.nh0(t+2); MFMA (m23)x(n23) ----
#pragma unroll
    for (int n = 0; n < 2; ++n) {
      int srow = 128 + wc * 32 + n * 16 + fr;       // nh=1: storage rows 128..255
      bfr[2 + n][0] = *(const bf16x8*)&sBc[srow * 64 + col0];
      bfr[2 + n][1] = *(const bf16x8*)&sBc[srow * 64 + col1];
    }
    if (t + 2 < nt) stage_B128(Bp + (size_t)(t + 2) * 64, ldb, sB[cur], 0, tid);
    __builtin_amdgcn_s_barrier();
    asm volatile("s_waitcnt lgkmcnt(0)" ::: "memory");
    __builtin_amdgcn_sched_barrier(0);
    __builtin_amdgcn_s_setprio(1);
#pragma unroll
    for (int m = 0; m < 2; ++m)
#pragma unroll
      for (int n = 0; n < 2; ++n) {
        acc[2 + m][2 + n] = mfma16(af[2 + m][0], bfr[2 + n][0], acc[2 + m][2 + n]);
        acc[2 + m][2 + n] = mfma16(af[2 + m][1], bfr[2 + n][1], acc[2 + m][2 + n]);
      }
    __builtin_amdgcn_s_setprio(0);
    __builtin_amdgcn_sched_barrier(0);
    __builtin_amdgcn_s_barrier();

    // ---- ph4: no reads; stage A.h1 + B.nh1 (t+2); MFMA (m01)x(n23) ----
    if (t + 2 < nt) {
      stage_A128(Ap + (size_t)(t + 2) * 64, lda, sA[cur], 1, tid);
      stage_B128(Bp + (size_t)(t + 2) * 64, ldb, sB[cur], 1, tid);
    }
    __builtin_amdgcn_s_setprio(1);
#pragma unroll
    for (int m = 0; m < 2; ++m)
#pragma unroll
      for (int n = 0; n < 2; ++n) {
        acc[m][2 + n] = mfma16(af[m][0], bfr[2 + n][0], acc[m][2 + n]);
        acc[m][2 + n] = mfma16(af[m][1], bfr[2 + n][1], acc[m][2 + n]);
      }
    __builtin_amdgcn_s_setprio(0);
    __builtin_amdgcn_sched_barrier(0);
    if (t + 2 < nt) {
      asm volatile("s_waitcnt vmcnt(6)" ::: "memory");
    } else if (t + 1 < nt) {
      asm volatile("s_waitcnt vmcnt(0)" ::: "memory");
    }
    __builtin_amdgcn_sched_barrier(0);
    __builtin_amdgcn_s_barrier();
  }

  unsigned short* Cb = reinterpret_cast<unsigned short*>(Cv) + (size_t)bz * (size_t)strideC;
  float* Cf = reinterpret_cast<float*>(Cv) + (size_t)bz * (size_t)strideC;
  const int rg = (lane >> 4) * 4;
#pragma unroll
  for (int m = 0; m < 4; ++m) {
    int r0 = rowBase + wr * 64 + m * 16 + rg;
#pragma unroll
    for (int n = 0; n < 4; ++n) {
      int cidx = colBase + wc * 64 + n * 16 + fr;
      float bv = 0.0f;
      if (HAS_BIAS) bv = bias[cidx];
#pragma unroll
      for (int j = 0; j < 4; ++j) {
        float v = acc[m][n][j] * alpha + bv;
        if (OUT_BF16)
          Cb[(size_t)(r0 + j) * ldc + cidx] = f2bf(v);
        else
          Cf[(size_t)(r0 + j) * ldc + cidx] = v;
      }
    }
  }
}

// --------------------------- V transpose -----------------------------------
__global__ void transpose_v(const unsigned short* __restrict__ qkv,
                            unsigned short* __restrict__ vt) {
  __shared__ unsigned short tile[32][33];
  const int b = blockIdx.z;
  const int d0 = blockIdx.x * 32;
  const int s0 = blockIdx.y * 32;
  const int tx = threadIdx.x, ty = threadIdx.y;
#pragma unroll
  for (int i = 0; i < 32; i += 8)
    tile[ty + i][tx] =
        qkv[(size_t)(b * 2048 + s0 + ty + i) * 3072 + 2048 + d0 + tx];
  __syncthreads();
#pragma unroll
  for (int i = 0; i < 32; i += 8)
    vt[((size_t)b * 1024 + d0 + ty + i) * 2048 + s0 + tx] = tile[tx][ty + i];
}

// --------------------------- row softmax (in place, bf16) ------------------
__global__ __launch_bounds__(256) void softmax_rows(unsigned short* __restrict__ s) {
  __shared__ float red[8];
  const size_t row = blockIdx.x;
  unsigned short* p = s + row * 2048;
  const int tid = threadIdx.x;

  ushort4 u0 = *reinterpret_cast<const ushort4*>(p + tid * 8);
  ushort4 u1 = *reinterpret_cast<const ushort4*>(p + tid * 8 + 4);
  float v[8];
  v[0] = bf2f(u0.x); v[1] = bf2f(u0.y); v[2] = bf2f(u0.z); v[3] = bf2f(u0.w);
  v[4] = bf2f(u1.x); v[5] = bf2f(u1.y); v[6] = bf2f(u1.z); v[7] = bf2f(u1.w);

  float mx = v[0];
#pragma unroll
  for (int j = 1; j < 8; ++j) mx = fmaxf(mx, v[j]);
#pragma unroll
  for (int off = 32; off; off >>= 1) mx = fmaxf(mx, __shfl_xor(mx, off));
  if ((tid & 63) == 0) red[tid >> 6] = mx;
  __syncthreads();
  mx = fmaxf(fmaxf(red[0], red[1]), fmaxf(red[2], red[3]));

  float e[8], sum = 0.0f;
#pragma unroll
  for (int j = 0; j < 8; ++j) { e[j] = __expf(v[j] - mx); sum += e[j]; }
#pragma unroll
  for (int off = 32; off; off >>= 1) sum += __shfl_xor(sum, off);
  if ((tid & 63) == 0) red[4 + (tid >> 6)] = sum;
  __syncthreads();
  sum = red[4] + red[5] + red[6] + red[7];
  const float inv = 1.0f / sum;

  ushort4 o0, o1;
  o0.x = f2bf(e[0] * inv); o0.y = f2bf(e[1] * inv);
  o0.z = f2bf(e[2] * inv); o0.w = f2bf(e[3] * inv);
  o1.x = f2bf(e[4] * inv); o1.y = f2bf(e[5] * inv);
  o1.z = f2bf(e[6] * inv); o1.w = f2bf(e[7] * inv);
  *reinterpret_cast<ushort4*>(p + tid * 8) = o0;
  *reinterpret_cast<ushort4*>(p + tid * 8 + 4) = o1;
}

// ---------------------------------------------------------------------------
extern "C" void kernel_launch(void* const* d_in, const int* in_sizes, int n_in,
                              void* d_out, int out_size, void* d_ws, size_t ws_size,
                              hipStream_t stream) {
  const float* x     = (const float*)d_in[0];
  const float* Wqkv  = (const float*)d_in[1];
  const float* bqkv  = (const float*)d_in[2];
  const float* Wproj = (const float*)d_in[3];
  const float* bproj = (const float*)d_in[4];
  float* out = (float*)d_out;

  char* ws = (char*)d_ws;
  unsigned short* qkv  = (unsigned short*)(ws + 0);          // 8192x3072 bf16
  unsigned short* xatt = (unsigned short*)(ws + 50331648);   // 8192x1024 bf16
  unsigned short* wq   = (unsigned short*)(ws + 67108864);   // 3072x1024 bf16
  unsigned short* wp   = (unsigned short*)(ws + 73400320);   // 1024x1024 bf16
  unsigned short* vt   = (unsigned short*)(ws + 75497472);   // 4x1024x2048 bf16
  unsigned short* sc   = (unsigned short*)(ws + 92274688);   // 4x2048x2048 bf16

  dim3 blk256(256), blk512(512);

  // 1. casts
  cvt_f32_bf16<<<2048, blk256, 0, stream>>>(x, xatt, 8192 * 1024);
  cvt_f32_bf16<<<1024, blk256, 0, stream>>>(Wqkv, wq, 3072 * 1024);
  cvt_f32_bf16<<<512, blk256, 0, stream>>>(Wproj, wp, 1024 * 1024);

  // 2. QKV projection: [8192,3072] (grid 12x64 = 768 = 3.0 rounds)
  gemm_bm128<true, true><<<dim3(12, 64, 1), blk512, 0, stream>>>(
      xatt, wq, qkv, bqkv, 8192, 3072, 1024, 1024, 1024, 3072, 0, 0, 0, 1.0f);

  // 3. V transpose -> Vt[b][d][s]
  transpose_v<<<dim3(32, 64, 4), dim3(32, 8), 0, stream>>>(qkv, vt);

  // 4. scores = Q @ K^T / 32  (grid 8x8x4 = 256, exact)
  gemm256<true, false><<<dim3(8, 8, 4), blk512, 0, stream>>>(
      qkv, qkv + 1024, sc, nullptr, 2048, 2048, 1024, 3072, 3072, 2048,
      2048LL * 3072, 2048LL * 3072, 2048LL * 2048, 0.03125f);

  // 5. softmax rows in place
  softmax_rows<<<8192, blk256, 0, stream>>>(sc);

  // 6. attn_out = P @ Vt  (grid 4x16x4 = 256, exact)
  gemm_bm128<true, false><<<dim3(4, 16, 4), blk512, 0, stream>>>(
      sc, vt, xatt, nullptr, 2048, 1024, 2048, 2048, 2048, 1024,
      2048LL * 2048, 1024LL * 2048, 2048LL * 1024, 1.0f);

  // 7. out = attn_out @ Wproj^T + b_proj  (grid 4x64 = 256, exact)
  gemm_bm128<false, true><<<dim3(4, 64, 1), blk512, 0, stream>>>(
      xatt, wp, out, bproj, 8192, 1024, 1024, 1024, 1024, 1024, 0, 0, 0, 1.0f);
}